// Round 6
// baseline (236.437 us; speedup 1.0000x reference)
//
#include <hip/hip_runtime.h>
#include <stdint.h>

// B=16 H=8 L=512 D=64; fp32 in/out. out = concat(output[128,512,64], attn[128,512,512]).
// Round-10 = Round-9 RESUBMIT (round-5 bench died at container level, no kernel signal).
// Round-9: wave re-partition j-interleaved (wave w owns jt tiles == w mod 4).
//   Old i-split made every wave read the WHOLE K chunk from LDS (32 ds_read_b128
//   /chunk/wave). Now each wave reads only its own 2 tiles/chunk (8 reads) and its
//   own V rows (4 reads/chunk): QK+PV LDS reads /4. Same MFMA count, same acc regs
//   (8x4), same DMA/barrier/vmcnt ledger as rounds 7/8 (proven). Cross-wave softmax
//   (MXW/SMW LDS reduce) + 2-pass LDS O-reduce aliased into BIG. LDS 68KB -> 2 blk/CU.
#define Ln 512
#define Dn 64
#define BHn 128
#define AOFF ((size_t)BHn*Ln*Dn)

typedef __attribute__((ext_vector_type(8))) short short8;   // 8 bf16 (4 VGPRs)
typedef __attribute__((ext_vector_type(4))) float f32x4;
typedef __attribute__((ext_vector_type(4))) unsigned int u32x4;
typedef __attribute__((ext_vector_type(2))) unsigned int u32x2;

__device__ __forceinline__ uint16_t f2bf(float f){
  uint32_t x = __float_as_uint(f);
  return (uint16_t)((x + 0x7FFFu + ((x>>16)&1u)) >> 16);   // RNE
}
__device__ __forceinline__ float bf2f(uint16_t u){ return __uint_as_float(((uint32_t)u)<<16); }
__device__ __forceinline__ uint32_t pack2(float a, float b){
  return (uint32_t)f2bf(a) | ((uint32_t)f2bf(b)<<16);
}
__device__ __forceinline__ void gld16(const uint16_t* g, uint16_t* l){
  __builtin_amdgcn_global_load_lds(
      (const __attribute__((address_space(1))) void*)g,
      (__attribute__((address_space(3))) void*)l, 16, 0, 0);
}

// ---- pre-pass: K -> KHI/KLO bf16, V -> V^T bf16, XOR-swizzled, chunk-major in ws ----
// K chunk layout (halves, per bh per chunk of 128 j): idx = j*64 + (k ^ ((j&7)<<3))
// V chunk layout (halves): idx = d*128 + (jl ^ ((d&7)<<3)), jl = j within chunk
extern "C" __global__ __launch_bounds__(256)
void attn_prep(const float* __restrict__ kg, const float* __restrict__ vg,
               uint16_t* __restrict__ khw, uint16_t* __restrict__ klw,
               uint16_t* __restrict__ vtw)
{
  const int t  = threadIdx.x;
  const int c  = blockIdx.x;          // j-chunk of 128
  const int bh = blockIdx.y;
  const size_t base = (size_t)bh*(Ln*Dn);
  const size_t wsb  = ((size_t)bh<<15) + ((size_t)c<<13);   // chunk base (halves)

  // K: thread pair per row; skh selects 32-k half
  {
    const int sj  = t>>1, skh = t&1;
    const float* kr = kg + base + (size_t)(c*128 + sj)*Dn + skh*32;
    const int sx = (sj&7)<<3;
    #pragma unroll
    for (int w2=0; w2<4; ++w2){
      f32x4 x0 = *(const f32x4*)(kr + w2*8);
      f32x4 x1 = *(const f32x4*)(kr + w2*8 + 4);
      uint32_t hw[4], lw[4];
      #pragma unroll
      for (int pi=0; pi<4; ++pi){
        float a0 = (pi<2) ? x0[pi*2]   : x1[(pi-2)*2];
        float a1 = (pi<2) ? x0[pi*2+1] : x1[(pi-2)*2+1];
        uint16_t h0 = f2bf(a0), h1 = f2bf(a1);
        hw[pi] = (uint32_t)h0 | ((uint32_t)h1<<16);
        lw[pi] = (uint32_t)f2bf(a0 - bf2f(h0)) | ((uint32_t)f2bf(a1 - bf2f(h1))<<16);
      }
      const size_t di = wsb + sj*64 + ((skh*32 + w2*8) ^ sx);
      *(u32x4*)(khw + di) = (u32x4){hw[0],hw[1],hw[2],hw[3]};
      *(u32x4*)(klw + di) = (u32x4){lw[0],lw[1],lw[2],lw[3]};
    }
  }

  // V: 4x4 register transpose -> VT[d][jl], swizzled
  #pragma unroll
  for (int it=0; it<2; ++it){
    const int j0 = (t>>4)*4 + it*64;    // [0,128)
    const int d0 = (t&15)*4;
    const float* vr = vg + base + (size_t)(c*128 + j0)*Dn + d0;
    f32x4 r0 = *(const f32x4*)(vr);
    f32x4 r1 = *(const f32x4*)(vr + Dn);
    f32x4 r2 = *(const f32x4*)(vr + 2*Dn);
    f32x4 r3 = *(const f32x4*)(vr + 3*Dn);
    #pragma unroll
    for (int qd=0; qd<4; ++qd){
      const int d = d0 + qd;
      u32x2 w; w.x = pack2(r0[qd], r1[qd]); w.y = pack2(r2[qd], r3[qd]);
      *(u32x2*)(vtw + wsb + d*128 + (j0 ^ ((d&7)<<3))) = w;
    }
  }
}

// ---- main: 64 q-rows/block; waves own interleaved jt tiles (jt == wv mod 4) ----
extern "C" __global__ __launch_bounds__(256, 2)
void attn_main3(const float* __restrict__ qg, const float* __restrict__ mg,
                const uint16_t* __restrict__ khw, const uint16_t* __restrict__ klw,
                const uint16_t* __restrict__ vtw, float* __restrict__ outg)
{
  // BIG 64KB: QK: Kbuf0 [0:16384) Kbuf1 [16384:32768) halves (KH 8192 + KL 8192 each)
  //           PV: VT0 [0:8192) VT1 [8192:16384); PW [16384:26624) (4 waves x 64 x 40)
  //           O-reduce: ORf f32 [0:8704) aliased after PV (barrier-gated)
  __shared__ __align__(16) uint16_t BIG[32768];
  __shared__ float CMV[512];
  __shared__ float MXW[256];   // [wv][i0..63] wave-local max
  __shared__ float SMW[256];   // [wv][i0..63] wave-local sum

  const int t    = threadIdx.x;
  const int lane = t & 63;
  const int wv   = t >> 6;
  const int li   = lane & 15;
  const int lq   = lane >> 4;
  const int kx   = (li&7)<<3;          // swizzle XOR (halves)

  // XCD swizzle: lin%8 = XCD; XCD k owns bh [k*16,k*16+16)
  const int lin = blockIdx.x + (blockIdx.y << 3);
  const int xcd = lin & 7;
  const int jj  = lin >> 3;
  const int bh  = (xcd << 4) + (jj >> 3);
  const int b   = bh >> 3;
  const int i0  = (jj & 7)*64;          // block's 64 query rows (all waves share)

  const size_t base = (size_t)bh*(Ln*Dn);
  const float* mrow = mg + b*Ln;
  const size_t wsbh = (size_t)bh << 15;

  uint16_t* PW = BIG + 16384 + wv*2560;   // 64 i-rows x 40 halves, wave-private

  auto issueK = [&](int c, int bsel){
    const size_t so = wsbh + ((size_t)c<<13) + (wv<<11) + (lane<<3);
    uint16_t* dh = BIG + bsel*16384 + (wv<<11);
    #pragma unroll
    for (int i=0;i<4;++i){
      gld16(khw + so + i*512, dh + i*512);
      gld16(klw + so + i*512, dh + 8192 + i*512);
    }
  };
  auto issueV = [&](int c, int bsel){
    const size_t so = wsbh + ((size_t)c<<13) + (wv<<11) + (lane<<3);
    uint16_t* dv = BIG + bsel*8192 + (wv<<11);
    #pragma unroll
    for (int i=0;i<4;++i) gld16(vtw + so + i*512, dv + i*512);
  };

  // ---- prologue: Q (4 i-tiles) + mask loads FIRST, then chunk-0 DMA ----
  f32x4 qa[4][2], qb[4][2];
  float rmvr[4];
  #pragma unroll
  for (int it=0; it<4; ++it){
    const float* qp = qg + base + (size_t)(i0 + it*16 + li)*Dn;
    #pragma unroll
    for (int kt=0; kt<2; ++kt){
      qa[it][kt] = *(const f32x4*)(qp + kt*32 + lq*8);
      qb[it][kt] = *(const f32x4*)(qp + kt*32 + lq*8 + 4);
    }
    rmvr[it] = mrow[i0 + it*16 + li];
  }
  float m0 = mrow[t], m1 = mrow[t+256];

  issueK(0, 0);

  CMV[t]     = (m0 < -9000.f) ? 1e9f : m0;
  CMV[t+256] = (m1 < -9000.f) ? 1e9f : m1;
  float rmv[4];
  #pragma unroll
  for (int it=0; it<4; ++it) rmv[it] = (rmvr[it] < -9000.f) ? 1e9f : rmvr[it];

  short8 qhi[4][2], qlo[4][2];
  #pragma unroll
  for (int it=0; it<4; ++it)
    #pragma unroll
    for (int kt=0; kt<2; ++kt)
      #pragma unroll
      for (int e=0; e<8; ++e){
        float x = (e<4) ? qa[it][kt][e] : qb[it][kt][e-4];
        uint16_t h = f2bf(x);
        qhi[it][kt][e] = (short)h;
        qlo[it][kt][e] = (short)f2bf(x - bf2f(h));
      }

  // acc[m][it]: S^T tile (jt = wv + 4m, it); lane holds S^T[jt*16+lq*4+r][it*16+li]
  f32x4 acc[8][4];
  #pragma unroll
  for (int m=0; m<8; ++m)
    #pragma unroll
    for (int it=0; it<4; ++it) acc[m][it] = (f32x4)0.f;

  // ---- QK: 4 chunks, dbuf DMA (ledger identical to round-7/8) ----
  #pragma unroll
  for (int c=0; c<4; ++c){
    if (c<3) issueK(c+1, (c+1)&1);
    if (c<3) asm volatile("s_waitcnt vmcnt(8)" ::: "memory");   // chunk c landed
    else     asm volatile("s_waitcnt vmcnt(4)" ::: "memory");   // K3 landed; V0 flies
    __builtin_amdgcn_sched_barrier(0);
    __builtin_amdgcn_s_barrier();
    __builtin_amdgcn_sched_barrier(0);
    const uint16_t* KHp = BIG + (c&1)*16384;
    const uint16_t* KLp = KHp + 8192;
    __builtin_amdgcn_s_setprio(1);
    #pragma unroll
    for (int mh=0; mh<2; ++mh){                    // wave's tiles in this chunk: m=2c+mh
      const int row = wv*16 + mh*64 + li;          // chunk-local j row
      #pragma unroll
      for (int kt=0; kt<2; ++kt){
        const int idx = row*64 + ((kt*32 + lq*8) ^ kx);
        short8 kh = *(const short8*)(KHp + idx);
        short8 kl = *(const short8*)(KLp + idx);
        #pragma unroll
        for (int it=0; it<4; ++it){
          f32x4 A = acc[2*c+mh][it];
          A = __builtin_amdgcn_mfma_f32_16x16x32_bf16(kh, qhi[it][kt], A, 0,0,0);
          A = __builtin_amdgcn_mfma_f32_16x16x32_bf16(kl, qhi[it][kt], A, 0,0,0);
          A = __builtin_amdgcn_mfma_f32_16x16x32_bf16(kh, qlo[it][kt], A, 0,0,0);
          acc[2*c+mh][it] = A;
        }
      }
    }
    __builtin_amdgcn_s_setprio(0);
    __builtin_amdgcn_sched_barrier(0);
    __builtin_amdgcn_s_barrier();
    __builtin_amdgcn_sched_barrier(0);
    if (c==2) issueV(0, 0);   // buf0 free after c=2 close
  }

  // ---- mask + scale + wave-local max (per i-tile) ----
  float mx[4] = {-3.4e38f,-3.4e38f,-3.4e38f,-3.4e38f};
  #pragma unroll
  for (int m=0; m<8; ++m){
    f32x4 cm = *(const f32x4*)(CMV + (wv + 4*m)*16 + lq*4);
    #pragma unroll
    for (int it=0; it<4; ++it)
      #pragma unroll
      for (int r=0; r<4; ++r){
        float v = (acc[m][it][r]*0.125f - rmv[it]) - cm[r];  // fp32 order matches ref
        acc[m][it][r] = v;
        mx[it] = fmaxf(mx[it], v);
      }
  }
  #pragma unroll
  for (int it=0; it<4; ++it){
    mx[it] = fmaxf(mx[it], __shfl_xor(mx[it], 16));
    mx[it] = fmaxf(mx[it], __shfl_xor(mx[it], 32));
  }
  if (lane < 16){
    #pragma unroll
    for (int it=0; it<4; ++it) MXW[wv*64 + it*16 + lane] = mx[it];
  }
  asm volatile("s_waitcnt lgkmcnt(0)" ::: "memory");
  __builtin_amdgcn_s_barrier();                  // raw: V0 DMA stays in flight
  float mxa[4];
  #pragma unroll
  for (int it=0; it<4; ++it)
    mxa[it] = fmaxf(fmaxf(MXW[it*16+li], MXW[64+it*16+li]),
                    fmaxf(MXW[128+it*16+li], MXW[192+it*16+li]));

  float sm[4] = {0.f,0.f,0.f,0.f};
  #pragma unroll
  for (int m=0; m<8; ++m)
    #pragma unroll
    for (int it=0; it<4; ++it)
      #pragma unroll
      for (int r=0; r<4; ++r){
        float e = __expf(acc[m][it][r] - mxa[it]);
        acc[m][it][r] = e;
        sm[it] += e;
      }
  #pragma unroll
  for (int it=0; it<4; ++it){
    sm[it] += __shfl_xor(sm[it], 16);
    sm[it] += __shfl_xor(sm[it], 32);
  }
  if (lane < 16){
    #pragma unroll
    for (int it=0; it<4; ++it) SMW[wv*64 + it*16 + lane] = sm[it];
  }
  asm volatile("s_waitcnt lgkmcnt(0)" ::: "memory");
  __builtin_amdgcn_s_barrier();
  float inv[4];
  #pragma unroll
  for (int it=0; it<4; ++it)
    inv[it] = 1.0f/((SMW[it*16+li] + SMW[64+it*16+li]) + (SMW[128+it*16+li] + SMW[192+it*16+li]));
  #pragma unroll
  for (int m=0; m<8; ++m)
    #pragma unroll
    for (int it=0; it<4; ++it) acc[m][it] = acc[m][it]*inv[it];   // normalized P

  // ---- PV: O^T partial per wave over its jt tiles; stores interleaved (same ledger) ----
  f32x4 oacc[4][4];   // [dt][it]; lane holds O^T[dt*16+lq*4+r][it*16+li] partial
  #pragma unroll
  for (int dt=0; dt<4; ++dt)
    #pragma unroll
    for (int it=0; it<4; ++it) oacc[dt][it] = (f32x4)0.f;

  float* arowb = outg + AOFF + (size_t)bh*Ln*Ln;
  const int jlq = wv*16 + (lq>>1)*64 + (lq&1)*8;   // V^T chunk-local j for A-frag

  #pragma unroll
  for (int c=0; c<4; ++c){
    if (c==0) asm volatile("s_waitcnt vmcnt(0)" ::: "memory");
    else      asm volatile("s_waitcnt vmcnt(8)" ::: "memory");   // V_c landed; prev stores fly
    __builtin_amdgcn_sched_barrier(0);
    __builtin_amdgcn_s_barrier();
    __builtin_amdgcn_sched_barrier(0);
    if (c<3) issueV(c+1, (c+1)&1);
    // P chunk: wave's tiles (m=2c,2c+1) x 4 it -> PW[i][jl] (jl in [0,32))
    #pragma unroll
    for (int mh=0; mh<2; ++mh)
      #pragma unroll
      for (int it=0; it<4; ++it){
        const f32x4 p = acc[2*c+mh][it];
        u32x2 w; w.x = pack2(p[0], p[1]); w.y = pack2(p[2], p[3]);
        *(u32x2*)(PW + (it*16+li)*40 + mh*16 + lq*4) = w;
      }
    asm volatile("s_waitcnt lgkmcnt(0)" ::: "memory");
    __builtin_amdgcn_sched_barrier(0);
    const uint16_t* VTp = BIG + (c&1)*8192;
    __builtin_amdgcn_s_setprio(1);
    short8 vb[4];
    #pragma unroll
    for (int dt=0; dt<4; ++dt)
      vb[dt] = *(const short8*)(VTp + (dt*16+li)*128 + (jlq ^ kx));   // V^T A-frag
    #pragma unroll
    for (int it=0; it<4; ++it){
      short8 pf = *(const short8*)(PW + (it*16+li)*40 + lq*8);        // P^T B-frag
      #pragma unroll
      for (int dt=0; dt<4; ++dt)
        oacc[dt][it] = __builtin_amdgcn_mfma_f32_16x16x32_bf16(vb[dt], pf, oacc[dt][it], 0,0,0);
    }
    __builtin_amdgcn_s_setprio(0);
    // attn stores for this chunk's tiles (8 f32x4/lane)
    #pragma unroll
    for (int mh=0; mh<2; ++mh)
      #pragma unroll
      for (int it=0; it<4; ++it)
        __builtin_nontemporal_store(acc[2*c+mh][it],
          (f32x4*)(arowb + (size_t)(i0 + it*16 + li)*Ln + (wv + 8*c + 4*mh)*16 + lq*4));
  }

  // ---- cross-wave O reduce: 2 passes of ORf[4][32][68] f32 aliased into BIG ----
  asm volatile("s_waitcnt lgkmcnt(0)" ::: "memory");
  __builtin_amdgcn_sched_barrier(0);
  __builtin_amdgcn_s_barrier();                  // all VT/PW reads done before alias
  __builtin_amdgcn_sched_barrier(0);
  float* ORf = (float*)BIG;
  #pragma unroll
  for (int pass=0; pass<2; ++pass){
    #pragma unroll
    for (int dh=0; dh<2; ++dh)
      #pragma unroll
      for (int it=0; it<4; ++it)
        #pragma unroll
        for (int r=0; r<4; ++r)
          ORf[wv*2176 + (dh*16 + lq*4 + r)*68 + it*16 + li] = oacc[pass*2+dh][it][r];
    asm volatile("s_waitcnt lgkmcnt(0)" ::: "memory");
    __builtin_amdgcn_s_barrier();
    #pragma unroll
    for (int k=0; k<8; ++k){
      const int x = t + 256*k;          // [0,2048): d = x&31, i = x>>5
      const int d = x & 31, i = x >> 5;
      float s = (ORf[d*68+i] + ORf[2176 + d*68+i]) + (ORf[4352 + d*68+i] + ORf[6528 + d*68+i]);
      outg[base + (size_t)(i0 + i)*Dn + pass*32 + d] = s;
    }
    if (pass==0){
      asm volatile("s_waitcnt lgkmcnt(0)" ::: "memory");
      __builtin_amdgcn_s_barrier();                // reads done before pass-1 overwrite
    }
  }
}

// ---------------- fallback (round-5 kernel) if workspace is too small ----------------
#define KSTR  72
#define VTSTR 136
#define FPSTRH 136

extern "C" __global__ __launch_bounds__(256, 2)
void attn_mfma(const float* __restrict__ qg, const float* __restrict__ kg,
               const float* __restrict__ vg, const float* __restrict__ mg,
               float* __restrict__ outg)
{
  __shared__ uint4 ldsraw[(36864 + 2048)/16];
  uint16_t* KHI = (uint16_t*)ldsraw;
  uint16_t* KLO = KHI + 128*KSTR;
  uint16_t* VT  = (uint16_t*)ldsraw;
  float*    CMV = (float*)((char*)ldsraw + 36864);

  const int t    = threadIdx.x;
  const int lane = t & 63;
  const int wv   = t >> 6;
  const int li   = lane & 15;
  const int lq   = lane >> 4;

  const int lin = blockIdx.x + (blockIdx.y << 3);
  const int xcd = lin & 7;
  const int jj  = lin >> 3;
  const int bh  = (xcd << 4) + (jj >> 3);
  const int b   = bh >> 3;
  const int i0  = (jj & 7)*64 + wv*16;

  const size_t base = (size_t)bh*(Ln*Dn);
  const float* mrow = mg + b*Ln;

  uint16_t* PW = (uint16_t*)((char*)ldsraw + 17408 + wv*(16*FPSTRH*2));

  {
    float m0 = mrow[t], m1 = mrow[t+256];
    CMV[t]     = (m0 < -9000.f) ? 1e9f : m0;
    CMV[t+256] = (m1 < -9000.f) ? 1e9f : m1;
  }

  short8 qhi[2], qlo[2];
  {
    const float* qrow = qg + base + (size_t)(i0 + li)*Dn;
    #pragma unroll
    for (int kt=0; kt<2; ++kt){
      const float* p = qrow + kt*32 + lq*8;
      f32x4 x0 = *(const f32x4*)p;
      f32x4 x1 = *(const f32x4*)(p+4);
      #pragma unroll
      for (int e=0; e<8; ++e){
        float x = (e<4) ? x0[e] : x1[e-4];
        uint16_t h = f2bf(x);
        qhi[kt][e] = (short)h;
        qlo[kt][e] = (short)f2bf(x - bf2f(h));
      }
    }
  }

  f32x4 acc[32];
  #pragma unroll
  for (int j=0; j<32; ++j) acc[j] = (f32x4)0.f;

  const int sj = t>>1, skh = t&1;
  #pragma unroll
  for (int c=0; c<4; ++c){
    __syncthreads();
    {
      const float* kr = kg + base + (size_t)(c*128 + sj)*Dn + skh*32;
      uint16_t* dhi = KHI + sj*KSTR + skh*32;
      uint16_t* dlo = KLO + sj*KSTR + skh*32;
      #pragma unroll
      for (int w2=0; w2<4; ++w2){
        f32x4 x0 = *(const f32x4*)(kr + w2*8);
        f32x4 x1 = *(const f32x4*)(kr + w2*8 + 4);
        uint32_t hw[4], lw[4];
        #pragma unroll
        for (int pi=0; pi<4; ++pi){
          float a0 = (pi<2) ? x0[pi*2]   : x1[(pi-2)*2];
          float a1 = (pi<2) ? x0[pi*2+1] : x1[(pi-2)*2+1];
          uint16_t h0 = f2bf(a0), h1 = f2bf(a1);
          hw[pi] = (uint32_t)h0 | ((uint32_t)h1<<16);
          lw[pi] = (uint32_t)f2bf(a0 - bf2f(h0)) | ((uint32_t)f2bf(a1 - bf2f(h1))<<16);
        }
        *(u32x4*)(dhi + w2*8) = (u32x4){hw[0],hw[1],hw[2],hw[3]};
        *(u32x4*)(dlo + w2*8) = (u32x4){lw[0],lw[1],lw[2],lw[3]};
      }
    }
    __syncthreads();
    #pragma unroll
    for (int jt=0; jt<8; ++jt){
      #pragma unroll
      for (int kt=0; kt<2; ++kt){
        const int off = (jt*16 + li)*KSTR + kt*32 + lq*8;
        short8 kh = *(const short8*)(KHI + off);
        short8 kl = *(const short8*)(KLO + off);
        f32x4 A = acc[c*8+jt];
        A = __builtin_amdgcn_mfma_f32_16x16x32_bf16(kh, qhi[kt], A, 0,0,0);
        A = __builtin_amdgcn_mfma_f32_16x16x32_bf16(kl, qhi[kt], A, 0,0,0);
        A = __builtin_amdgcn_mfma_f32_16x16x32_bf16(kh, qlo[kt], A, 0,0,0);
        acc[c*8+jt] = A;
      }
    }
  }

  {
    float mv = mrow[i0 + li];
    const float rmv = (mv < -9000.f) ? 1e9f : mv;
    #pragma unroll
    for (int jt=0; jt<32; ++jt){
      f32x4 cm = *(const f32x4*)(CMV + jt*16 + lq*4);
      #pragma unroll
      for (int r=0; r<4; ++r)
        acc[jt][r] = (acc[jt][r]*0.125f - rmv) - cm[r];
    }
  }
  float mx = -3.4e38f;
  #pragma unroll
  for (int jt=0; jt<32; ++jt)
    #pragma unroll
    for (int r=0; r<4; ++r) mx = fmaxf(mx, acc[jt][r]);
  mx = fmaxf(mx, __shfl_xor(mx, 16));
  mx = fmaxf(mx, __shfl_xor(mx, 32));
  float sum = 0.f;
  #pragma unroll
  for (int jt=0; jt<32; ++jt)
    #pragma unroll
    for (int r=0; r<4; ++r){ float e = __expf(acc[jt][r]-mx); acc[jt][r] = e; sum += e; }
  sum += __shfl_xor(sum, 16);
  sum += __shfl_xor(sum, 32);
  const float inv = 1.0f/sum;

  {
    float* arow = outg + AOFF + (size_t)bh*Ln*Ln + (size_t)(i0+li)*Ln;
    #pragma unroll
    for (int jt=0; jt<32; ++jt){
      f32x4 p = acc[jt]*inv;
      acc[jt] = p;
      *(f32x4*)(arow + jt*16 + lq*4) = p;
    }
  }

  f32x4 oacc[4];
  #pragma unroll
  for (int dt=0; dt<4; ++dt) oacc[dt] = (f32x4)0.f;

  #pragma unroll
  for (int c=0; c<4; ++c){
    __syncthreads();
    #pragma unroll
    for (int it=0; it<2; ++it){
      const int j0 = (t>>4)*4 + it*64;
      const int d0 = (t&15)*4;
      const float* vr = vg + base + (size_t)(c*128 + j0)*Dn + d0;
      f32x4 r0 = *(const f32x4*)(vr);
      f32x4 r1 = *(const f32x4*)(vr + Dn);
      f32x4 r2 = *(const f32x4*)(vr + 2*Dn);
      f32x4 r3 = *(const f32x4*)(vr + 3*Dn);
      #pragma unroll
      for (int qd=0; qd<4; ++qd){
        u32x2 w; w.x = pack2(r0[qd], r1[qd]); w.y = pack2(r2[qd], r3[qd]);
        *(u32x2*)(VT + (d0+qd)*VTSTR + j0) = w;
      }
    }
    __syncthreads();
    #pragma unroll
    for (int jtl=0; jtl<8; ++jtl){
      const f32x4 p = acc[c*8+jtl];
      u32x2 w; w.x = pack2(p[0], p[1]); w.y = pack2(p[2], p[3]);
      *(u32x2*)(PW + li*FPSTRH + jtl*16 + lq*4) = w;
    }
    asm volatile("s_waitcnt lgkmcnt(0)" ::: "memory");
    #pragma unroll
    for (int c32=0; c32<4; ++c32){
      short8 pf = *(const short8*)(PW + li*FPSTRH + c32*32 + lq*8);
      #pragma unroll
      for (int dt=0; dt<4; ++dt){
        short8 vb = *(const short8*)(VT + (dt*16+li)*VTSTR + c32*32 + lq*8);
        oacc[dt] = __builtin_amdgcn_mfma_f32_16x16x32_bf16(vb, pf, oacc[dt], 0,0,0);
      }
    }
  }

  #pragma unroll
  for (int dt=0; dt<4; ++dt)
    *(f32x4*)(outg + base + (size_t)(i0+li)*Dn + dt*16 + lq*4) = oacc[dt];
}

extern "C" void kernel_launch(void* const* d_in, const int* in_sizes, int n_in,
                              void* d_out, int out_size, void* d_ws, size_t ws_size,
                              hipStream_t stream)
{
  (void)in_sizes; (void)n_in; (void)out_size;
  const float* qg = (const float*)d_in[0];
  const float* kg = (const float*)d_in[1];
  const float* vg = (const float*)d_in[2];
  const float* mg = (const float*)d_in[3];
  float* outg = (float*)d_out;

  const size_t WS_NEED = 25165824;   // KHI 8.39MB + KLO 8.39MB + VT 8.39MB
  if (d_ws && ws_size >= WS_NEED){
    uint16_t* khw = (uint16_t*)d_ws;
    uint16_t* klw = (uint16_t*)((char*)d_ws + 8388608);
    uint16_t* vtw = (uint16_t*)((char*)d_ws + 16777216);
    attn_prep<<<dim3(4, BHn), 256, 0, stream>>>(kg, vg, khw, klw, vtw);
    attn_main3<<<dim3(Ln/64, BHn), 256, 0, stream>>>(qg, mg, khw, klw, vtw, outg);
  } else {
    attn_mfma<<<dim3(Ln/64, BHn), 256, 0, stream>>>(qg, kg, vg, mg, outg);
  }
}

// Round 7
// 220.508 us; speedup vs baseline: 1.0722x; 1.0722x over previous
//
#include <hip/hip_runtime.h>
#include <stdint.h>

// B=16 H=8 L=512 D=64; fp32 in/out. out = concat(output[128,512,64], attn[128,512,512]).
// Round-11 = Round-8 base (best: 231.2us total, main ~75us) with ONE change:
//   attn stores NORMAL instead of nontemporal. NT bypasses L2 write-combining;
//   our 64B-piece/2KB-stride pattern then hits DRAM as partial lines (~50% eff,
//   observed 2.3 TB/s vs fill kernel's 6.8 TB/s on the same buffer). Normal
//   stores let L2 merge same-phase 64B pieces into full 128B lines.
//   (Round-9 j-interleave reverted: 236.4us, LDS-read saving < added overhead.)
#define Ln 512
#define Dn 64
#define BHn 128
#define AOFF ((size_t)BHn*Ln*Dn)

typedef __attribute__((ext_vector_type(8))) short short8;   // 8 bf16 (4 VGPRs)
typedef __attribute__((ext_vector_type(4))) float f32x4;
typedef __attribute__((ext_vector_type(4))) unsigned int u32x4;
typedef __attribute__((ext_vector_type(2))) unsigned int u32x2;

__device__ __forceinline__ uint16_t f2bf(float f){
  uint32_t x = __float_as_uint(f);
  return (uint16_t)((x + 0x7FFFu + ((x>>16)&1u)) >> 16);   // RNE
}
__device__ __forceinline__ float bf2f(uint16_t u){ return __uint_as_float(((uint32_t)u)<<16); }
__device__ __forceinline__ uint32_t pack2(float a, float b){
  return (uint32_t)f2bf(a) | ((uint32_t)f2bf(b)<<16);
}
__device__ __forceinline__ void gld16(const uint16_t* g, uint16_t* l){
  __builtin_amdgcn_global_load_lds(
      (const __attribute__((address_space(1))) void*)g,
      (__attribute__((address_space(3))) void*)l, 16, 0, 0);
}

// ---- pre-pass: K -> KHI/KLO bf16, V -> V^T bf16, XOR-swizzled, chunk-major in ws ----
// K chunk layout (halves, per bh per chunk of 128 j): idx = j*64 + (k ^ ((j&7)<<3))
// V chunk layout (halves): idx = d*128 + (jl ^ ((d&7)<<3)), jl = j within chunk
extern "C" __global__ __launch_bounds__(256)
void attn_prep(const float* __restrict__ kg, const float* __restrict__ vg,
               uint16_t* __restrict__ khw, uint16_t* __restrict__ klw,
               uint16_t* __restrict__ vtw)
{
  const int t  = threadIdx.x;
  const int c  = blockIdx.x;          // j-chunk of 128
  const int bh = blockIdx.y;
  const size_t base = (size_t)bh*(Ln*Dn);
  const size_t wsb  = ((size_t)bh<<15) + ((size_t)c<<13);   // chunk base (halves)

  // K: thread pair per row; skh selects 32-k half
  {
    const int sj  = t>>1, skh = t&1;
    const float* kr = kg + base + (size_t)(c*128 + sj)*Dn + skh*32;
    const int sx = (sj&7)<<3;
    #pragma unroll
    for (int w2=0; w2<4; ++w2){
      f32x4 x0 = *(const f32x4*)(kr + w2*8);
      f32x4 x1 = *(const f32x4*)(kr + w2*8 + 4);
      uint32_t hw[4], lw[4];
      #pragma unroll
      for (int pi=0; pi<4; ++pi){
        float a0 = (pi<2) ? x0[pi*2]   : x1[(pi-2)*2];
        float a1 = (pi<2) ? x0[pi*2+1] : x1[(pi-2)*2+1];
        uint16_t h0 = f2bf(a0), h1 = f2bf(a1);
        hw[pi] = (uint32_t)h0 | ((uint32_t)h1<<16);
        lw[pi] = (uint32_t)f2bf(a0 - bf2f(h0)) | ((uint32_t)f2bf(a1 - bf2f(h1))<<16);
      }
      const size_t di = wsb + sj*64 + ((skh*32 + w2*8) ^ sx);
      *(u32x4*)(khw + di) = (u32x4){hw[0],hw[1],hw[2],hw[3]};
      *(u32x4*)(klw + di) = (u32x4){lw[0],lw[1],lw[2],lw[3]};
    }
  }

  // V: 4x4 register transpose -> VT[d][jl], swizzled
  #pragma unroll
  for (int it=0; it<2; ++it){
    const int j0 = (t>>4)*4 + it*64;    // [0,128)
    const int d0 = (t&15)*4;
    const float* vr = vg + base + (size_t)(c*128 + j0)*Dn + d0;
    f32x4 r0 = *(const f32x4*)(vr);
    f32x4 r1 = *(const f32x4*)(vr + Dn);
    f32x4 r2 = *(const f32x4*)(vr + 2*Dn);
    f32x4 r3 = *(const f32x4*)(vr + 3*Dn);
    #pragma unroll
    for (int qd=0; qd<4; ++qd){
      const int d = d0 + qd;
      u32x2 w; w.x = pack2(r0[qd], r1[qd]); w.y = pack2(r2[qd], r3[qd]);
      *(u32x2*)(vtw + wsb + d*128 + (j0 ^ ((d&7)<<3))) = w;
    }
  }
}

// ---- main: 64 q-rows/block, 4 waves x 16 rows; DMA-staged dbuf chunks ----
extern "C" __global__ __launch_bounds__(256, 2)
void attn_main2(const float* __restrict__ qg, const float* __restrict__ mg,
                const uint16_t* __restrict__ khw, const uint16_t* __restrict__ klw,
                const uint16_t* __restrict__ vtw, float* __restrict__ outg)
{
  // 64KB BIG: QK phase KH0[8192] KL0[8192] KH1[8192] KL1[8192] (halves)
  //           PV phase VT0[8192] VT1[8192] P[4 waves][2176]
  // + CMV[512] f32 column-mask terms (lgkm domain; keeps softmax off vmem)
  __shared__ __align__(16) uint16_t BIG[32768];
  __shared__ float CMV[512];

  const int t    = threadIdx.x;
  const int lane = t & 63;
  const int wv   = t >> 6;
  const int li   = lane & 15;
  const int lq   = lane >> 4;
  const int kx   = (li&7)<<3;          // swizzle XOR (halves)

  // XCD swizzle: lin%8 = XCD; XCD k owns bh [k*16,k*16+16)
  const int lin = blockIdx.x + (blockIdx.y << 3);
  const int xcd = lin & 7;
  const int jj  = lin >> 3;
  const int bh  = (xcd << 4) + (jj >> 3);
  const int b   = bh >> 3;
  const int i0  = (jj & 7)*64 + wv*16;

  const size_t base = (size_t)bh*(Ln*Dn);
  const float* mrow = mg + b*Ln;
  const size_t wsbh = (size_t)bh << 15;

  uint16_t* PW = BIG + 16384 + wv*2176;

  auto issueK = [&](int c, int bsel){
    const size_t so = wsbh + ((size_t)c<<13) + (wv<<11) + (lane<<3);
    uint16_t* dh = BIG + bsel*16384 + (wv<<11);
    #pragma unroll
    for (int i=0;i<4;++i){
      gld16(khw + so + i*512, dh + i*512);
      gld16(klw + so + i*512, dh + 8192 + i*512);
    }
  };
  auto issueV = [&](int c, int bsel){
    const size_t so = wsbh + ((size_t)c<<13) + (wv<<11) + (lane<<3);
    uint16_t* dv = BIG + bsel*8192 + (wv<<11);
    #pragma unroll
    for (int i=0;i<4;++i) gld16(vtw + so + i*512, dv + i*512);
  };

  // ---- prologue: Q + mask loads FIRST, then chunk-0 DMA (Q-waits leave DMA alive) ----
  const float* qrow = qg + base + (size_t)(i0 + li)*Dn;
  f32x4 qx0a = *(const f32x4*)(qrow + lq*8);
  f32x4 qx0b = *(const f32x4*)(qrow + lq*8 + 4);
  f32x4 qx1a = *(const f32x4*)(qrow + 32 + lq*8);
  f32x4 qx1b = *(const f32x4*)(qrow + 32 + lq*8 + 4);
  float m0 = mrow[t], m1 = mrow[t+256];
  float mv = mrow[i0 + li];

  issueK(0, 0);

  CMV[t]     = (m0 < -9000.f) ? 1e9f : m0;
  CMV[t+256] = (m1 < -9000.f) ? 1e9f : m1;
  const float rmv = (mv < -9000.f) ? 1e9f : mv;

  short8 qhi[2], qlo[2];
  #pragma unroll
  for (int kt=0; kt<2; ++kt){
    f32x4 xa = kt ? qx1a : qx0a;
    f32x4 xb = kt ? qx1b : qx0b;
    #pragma unroll
    for (int e=0; e<8; ++e){
      float x = (e<4) ? xa[e] : xb[e-4];
      uint16_t h = f2bf(x);
      qhi[kt][e] = (short)h;
      qlo[kt][e] = (short)f2bf(x - bf2f(h));
    }
  }

  f32x4 acc[32];
  #pragma unroll
  for (int j=0; j<32; ++j) acc[j] = (f32x4)0.f;

  // ---- QK: 4 chunks, double-buffered DMA; raw barriers + counted vmcnt ----
  #pragma unroll
  for (int c=0; c<4; ++c){
    if (c<3) issueK(c+1, (c+1)&1);
    if (c<3) asm volatile("s_waitcnt vmcnt(8)" ::: "memory");   // chunk c landed (mine)
    else     asm volatile("s_waitcnt vmcnt(4)" ::: "memory");   // K3 landed; V0 stays in flight
    __builtin_amdgcn_sched_barrier(0);
    __builtin_amdgcn_s_barrier();                                // all waves' portions landed
    __builtin_amdgcn_sched_barrier(0);
    const uint16_t* KHp = BIG + (c&1)*16384;
    const uint16_t* KLp = KHp + 8192;
    __builtin_amdgcn_s_setprio(1);
    #pragma unroll
    for (int jt=0; jt<8; ++jt){
      #pragma unroll
      for (int kt=0; kt<2; ++kt){
        const int idx = (jt*16 + li)*64 + ((kt*32 + lq*8) ^ kx);
        short8 kh = *(const short8*)(KHp + idx);
        short8 kl = *(const short8*)(KLp + idx);
        f32x4 A = acc[c*8+jt];
        A = __builtin_amdgcn_mfma_f32_16x16x32_bf16(kh, qhi[kt], A, 0,0,0);
        A = __builtin_amdgcn_mfma_f32_16x16x32_bf16(kl, qhi[kt], A, 0,0,0);
        A = __builtin_amdgcn_mfma_f32_16x16x32_bf16(kh, qlo[kt], A, 0,0,0);
        acc[c*8+jt] = A;
      }
    }
    __builtin_amdgcn_s_setprio(0);
    __builtin_amdgcn_sched_barrier(0);
    __builtin_amdgcn_s_barrier();                                // readers done before buf reuse
    __builtin_amdgcn_sched_barrier(0);
    if (c==2) issueV(0, 0);   // buf0 free after c=2 close; overlaps chunk-3 compute + softmax
  }

  // ---- mask + scale (CMV from LDS; pure lgkm/VALU — V0 DMA untouched) ----
  #pragma unroll
  for (int jt=0; jt<32; ++jt){
    f32x4 cm = *(const f32x4*)(CMV + jt*16 + lq*4);
    #pragma unroll
    for (int r=0; r<4; ++r)
      acc[jt][r] = (acc[jt][r]*0.125f - rmv) - cm[r];   // fp32 order matches ref
  }

  // ---- softmax over j (wave-local: lane owns full row across quads) ----
  float mx = -3.4e38f;
  #pragma unroll
  for (int jt=0; jt<32; ++jt)
    #pragma unroll
    for (int r=0; r<4; ++r) mx = fmaxf(mx, acc[jt][r]);
  mx = fmaxf(mx, __shfl_xor(mx, 16));
  mx = fmaxf(mx, __shfl_xor(mx, 32));
  float sum = 0.f;
  #pragma unroll
  for (int jt=0; jt<32; ++jt)
    #pragma unroll
    for (int r=0; r<4; ++r){ float e = __expf(acc[jt][r]-mx); acc[jt][r] = e; sum += e; }
  sum += __shfl_xor(sum, 16);
  sum += __shfl_xor(sum, 32);
  const float inv = 1.0f/sum;
  #pragma unroll
  for (int jt=0; jt<32; ++jt) acc[jt] = acc[jt]*inv;   // normalized P (also attn output)

  // ---- PV with per-chunk attn stores; ledger: 8 newest vmem = prev chunk's stores ----
  f32x4 oacc[4];
  #pragma unroll
  for (int dt=0; dt<4; ++dt) oacc[dt] = (f32x4)0.f;

  float* arow = outg + AOFF + (size_t)bh*Ln*Ln + (size_t)(i0+li)*Ln;

  #pragma unroll
  for (int c=0; c<4; ++c){
    if (c==0) asm volatile("s_waitcnt vmcnt(0)" ::: "memory");   // V0 landed (only V0 out)
    else      asm volatile("s_waitcnt vmcnt(8)" ::: "memory");   // V_c landed; prev stores fly
    __builtin_amdgcn_sched_barrier(0);
    __builtin_amdgcn_s_barrier();                                 // all waves; gates buf reuse
    __builtin_amdgcn_sched_barrier(0);
    if (c<3) issueV(c+1, (c+1)&1);
    #pragma unroll
    for (int jtl=0; jtl<8; ++jtl){                                // P chunk rows (wave-private)
      const f32x4 p = acc[c*8+jtl];
      u32x2 w; w.x = pack2(p[0], p[1]); w.y = pack2(p[2], p[3]);
      *(u32x2*)(PW + li*136 + jtl*16 + lq*4) = w;
    }
    asm volatile("s_waitcnt lgkmcnt(0)" ::: "memory");            // P visible within wave
    __builtin_amdgcn_sched_barrier(0);
    const uint16_t* VTp = BIG + (c&1)*8192;
    __builtin_amdgcn_s_setprio(1);
    #pragma unroll
    for (int c32=0; c32<4; ++c32){
      short8 pf = *(const short8*)(PW + li*136 + c32*32 + lq*8);           // P^T B-frag
      #pragma unroll
      for (int dt=0; dt<4; ++dt){
        short8 vb = *(const short8*)(VTp + (dt*16+li)*128 + ((c32*32+lq*8) ^ kx)); // V^T A-frag
        oacc[dt] = __builtin_amdgcn_mfma_f32_16x16x32_bf16(vb, pf, oacc[dt], 0,0,0);
      }
    }
    __builtin_amdgcn_s_setprio(0);
    // attn stores for chunk c (8 f32x4/lane) — NORMAL stores: L2 merges the
    // 64B pieces written by this wave this phase into full 128B lines.
    #pragma unroll
    for (int jtl=0; jtl<8; ++jtl)
      *(f32x4*)(arow + (c*8+jtl)*16 + lq*4) = acc[c*8+jtl];
  }

  // ---- store O (O^T C-layout) ----
  #pragma unroll
  for (int dt=0; dt<4; ++dt)
    *(f32x4*)(outg + base + (size_t)(i0+li)*Dn + dt*16 + lq*4) = oacc[dt];
}

// ---------------- fallback (round-5 kernel) if workspace is too small ----------------
#define KSTR  72
#define VTSTR 136
#define FPSTRH 136

extern "C" __global__ __launch_bounds__(256, 2)
void attn_mfma(const float* __restrict__ qg, const float* __restrict__ kg,
               const float* __restrict__ vg, const float* __restrict__ mg,
               float* __restrict__ outg)
{
  __shared__ uint4 ldsraw[(36864 + 2048)/16];
  uint16_t* KHI = (uint16_t*)ldsraw;
  uint16_t* KLO = KHI + 128*KSTR;
  uint16_t* VT  = (uint16_t*)ldsraw;
  float*    CMV = (float*)((char*)ldsraw + 36864);

  const int t    = threadIdx.x;
  const int lane = t & 63;
  const int wv   = t >> 6;
  const int li   = lane & 15;
  const int lq   = lane >> 4;

  const int lin = blockIdx.x + (blockIdx.y << 3);
  const int xcd = lin & 7;
  const int jj  = lin >> 3;
  const int bh  = (xcd << 4) + (jj >> 3);
  const int b   = bh >> 3;
  const int i0  = (jj & 7)*64 + wv*16;

  const size_t base = (size_t)bh*(Ln*Dn);
  const float* mrow = mg + b*Ln;

  uint16_t* PW = (uint16_t*)((char*)ldsraw + 17408 + wv*(16*FPSTRH*2));

  {
    float m0 = mrow[t], m1 = mrow[t+256];
    CMV[t]     = (m0 < -9000.f) ? 1e9f : m0;
    CMV[t+256] = (m1 < -9000.f) ? 1e9f : m1;
  }

  short8 qhi[2], qlo[2];
  {
    const float* qrow = qg + base + (size_t)(i0 + li)*Dn;
    #pragma unroll
    for (int kt=0; kt<2; ++kt){
      const float* p = qrow + kt*32 + lq*8;
      f32x4 x0 = *(const f32x4*)p;
      f32x4 x1 = *(const f32x4*)(p+4);
      #pragma unroll
      for (int e=0; e<8; ++e){
        float x = (e<4) ? x0[e] : x1[e-4];
        uint16_t h = f2bf(x);
        qhi[kt][e] = (short)h;
        qlo[kt][e] = (short)f2bf(x - bf2f(h));
      }
    }
  }

  f32x4 acc[32];
  #pragma unroll
  for (int j=0; j<32; ++j) acc[j] = (f32x4)0.f;

  const int sj = t>>1, skh = t&1;
  #pragma unroll
  for (int c=0; c<4; ++c){
    __syncthreads();
    {
      const float* kr = kg + base + (size_t)(c*128 + sj)*Dn + skh*32;
      uint16_t* dhi = KHI + sj*KSTR + skh*32;
      uint16_t* dlo = KLO + sj*KSTR + skh*32;
      #pragma unroll
      for (int w2=0; w2<4; ++w2){
        f32x4 x0 = *(const f32x4*)(kr + w2*8);
        f32x4 x1 = *(const f32x4*)(kr + w2*8 + 4);
        uint32_t hw[4], lw[4];
        #pragma unroll
        for (int pi=0; pi<4; ++pi){
          float a0 = (pi<2) ? x0[pi*2]   : x1[(pi-2)*2];
          float a1 = (pi<2) ? x0[pi*2+1] : x1[(pi-2)*2+1];
          uint16_t h0 = f2bf(a0), h1 = f2bf(a1);
          hw[pi] = (uint32_t)h0 | ((uint32_t)h1<<16);
          lw[pi] = (uint32_t)f2bf(a0 - bf2f(h0)) | ((uint32_t)f2bf(a1 - bf2f(h1))<<16);
        }
        *(u32x4*)(dhi + w2*8) = (u32x4){hw[0],hw[1],hw[2],hw[3]};
        *(u32x4*)(dlo + w2*8) = (u32x4){lw[0],lw[1],lw[2],lw[3]};
      }
    }
    __syncthreads();
    #pragma unroll
    for (int jt=0; jt<8; ++jt){
      #pragma unroll
      for (int kt=0; kt<2; ++kt){
        const int off = (jt*16 + li)*KSTR + kt*32 + lq*8;
        short8 kh = *(const short8*)(KHI + off);
        short8 kl = *(const short8*)(KLO + off);
        f32x4 A = acc[c*8+jt];
        A = __builtin_amdgcn_mfma_f32_16x16x32_bf16(kh, qhi[kt], A, 0,0,0);
        A = __builtin_amdgcn_mfma_f32_16x16x32_bf16(kl, qhi[kt], A, 0,0,0);
        A = __builtin_amdgcn_mfma_f32_16x16x32_bf16(kh, qlo[kt], A, 0,0,0);
        acc[c*8+jt] = A;
      }
    }
  }

  {
    float mv = mrow[i0 + li];
    const float rmv = (mv < -9000.f) ? 1e9f : mv;
    #pragma unroll
    for (int jt=0; jt<32; ++jt){
      f32x4 cm = *(const f32x4*)(CMV + jt*16 + lq*4);
      #pragma unroll
      for (int r=0; r<4; ++r)
        acc[jt][r] = (acc[jt][r]*0.125f - rmv) - cm[r];
    }
  }
  float mx = -3.4e38f;
  #pragma unroll
  for (int jt=0; jt<32; ++jt)
    #pragma unroll
    for (int r=0; r<4; ++r) mx = fmaxf(mx, acc[jt][r]);
  mx = fmaxf(mx, __shfl_xor(mx, 16));
  mx = fmaxf(mx, __shfl_xor(mx, 32));
  float sum = 0.f;
  #pragma unroll
  for (int jt=0; jt<32; ++jt)
    #pragma unroll
    for (int r=0; r<4; ++r){ float e = __expf(acc[jt][r]-mx); acc[jt][r] = e; sum += e; }
  sum += __shfl_xor(sum, 16);
  sum += __shfl_xor(sum, 32);
  const float inv = 1.0f/sum;

  {
    float* arow = outg + AOFF + (size_t)bh*Ln*Ln + (size_t)(i0+li)*Ln;
    #pragma unroll
    for (int jt=0; jt<32; ++jt){
      f32x4 p = acc[jt]*inv;
      acc[jt] = p;
      *(f32x4*)(arow + jt*16 + lq*4) = p;
    }
  }

  f32x4 oacc[4];
  #pragma unroll
  for (int dt=0; dt<4; ++dt) oacc[dt] = (f32x4)0.f;

  #pragma unroll
  for (int c=0; c<4; ++c){
    __syncthreads();
    #pragma unroll
    for (int it=0; it<2; ++it){
      const int j0 = (t>>4)*4 + it*64;
      const int d0 = (t&15)*4;
      const float* vr = vg + base + (size_t)(c*128 + j0)*Dn + d0;
      f32x4 r0 = *(const f32x4*)(vr);
      f32x4 r1 = *(const f32x4*)(vr + Dn);
      f32x4 r2 = *(const f32x4*)(vr + 2*Dn);
      f32x4 r3 = *(const f32x4*)(vr + 3*Dn);
      #pragma unroll
      for (int qd=0; qd<4; ++qd){
        u32x2 w; w.x = pack2(r0[qd], r1[qd]); w.y = pack2(r2[qd], r3[qd]);
        *(u32x2*)(VT + (d0+qd)*VTSTR + j0) = w;
      }
    }
    __syncthreads();
    #pragma unroll
    for (int jtl=0; jtl<8; ++jtl){
      const f32x4 p = acc[c*8+jtl];
      u32x2 w; w.x = pack2(p[0], p[1]); w.y = pack2(p[2], p[3]);
      *(u32x2*)(PW + li*FPSTRH + jtl*16 + lq*4) = w;
    }
    asm volatile("s_waitcnt lgkmcnt(0)" ::: "memory");
    #pragma unroll
    for (int c32=0; c32<4; ++c32){
      short8 pf = *(const short8*)(PW + li*FPSTRH + c32*32 + lq*8);
      #pragma unroll
      for (int dt=0; dt<4; ++dt){
        short8 vb = *(const short8*)(VT + (dt*16+li)*VTSTR + c32*32 + lq*8);
        oacc[dt] = __builtin_amdgcn_mfma_f32_16x16x32_bf16(vb, pf, oacc[dt], 0,0,0);
      }
    }
  }

  #pragma unroll
  for (int dt=0; dt<4; ++dt)
    *(f32x4*)(outg + base + (size_t)(i0+li)*Dn + dt*16 + lq*4) = oacc[dt];
}

extern "C" void kernel_launch(void* const* d_in, const int* in_sizes, int n_in,
                              void* d_out, int out_size, void* d_ws, size_t ws_size,
                              hipStream_t stream)
{
  (void)in_sizes; (void)n_in; (void)out_size;
  const float* qg = (const float*)d_in[0];
  const float* kg = (const float*)d_in[1];
  const float* vg = (const float*)d_in[2];
  const float* mg = (const float*)d_in[3];
  float* outg = (float*)d_out;

  const size_t WS_NEED = 25165824;   // KHI 8.39MB + KLO 8.39MB + VT 8.39MB
  if (d_ws && ws_size >= WS_NEED){
    uint16_t* khw = (uint16_t*)d_ws;
    uint16_t* klw = (uint16_t*)((char*)d_ws + 8388608);
    uint16_t* vtw = (uint16_t*)((char*)d_ws + 16777216);
    attn_prep<<<dim3(4, BHn), 256, 0, stream>>>(kg, vg, khw, klw, vtw);
    attn_main2<<<dim3(Ln/64, BHn), 256, 0, stream>>>(qg, mg, khw, klw, vtw, outg);
  } else {
    attn_mfma<<<dim3(Ln/64, BHn), 256, 0, stream>>>(qg, kg, vg, mg, outg);
  }
}

// Round 8
// 216.208 us; speedup vs baseline: 1.0936x; 1.0199x over previous
//
#include <hip/hip_runtime.h>
#include <stdint.h>

// B=16 H=8 L=512 D=64; fp32 in/out. out = concat(output[128,512,64], attn[128,512,512]).
// Round-12 = Round-11 base (best: 220.5us; NT->normal stores confirmed +10.7) with:
//  1) prep re-grid (4,128)->(8,128): half-chunks of 64 rows. Prep was 18us for 58MB
//     (3.2 TB/s, latency-bound at 2 blocks/CU); 1024 blocks -> 4 blocks/CU,
//     16 waves/CU. Identical ws layout/arithmetic, same store widths.
//  2) PV P-pack hoisted above the vmcnt wait (pure VALU on long-ready acc) so the
//     post-barrier path is P-store -> lgkmcnt -> MFMA with no VALU preamble.
#define Ln 512
#define Dn 64
#define BHn 128
#define AOFF ((size_t)BHn*Ln*Dn)

typedef __attribute__((ext_vector_type(8))) short short8;   // 8 bf16 (4 VGPRs)
typedef __attribute__((ext_vector_type(4))) float f32x4;
typedef __attribute__((ext_vector_type(4))) unsigned int u32x4;
typedef __attribute__((ext_vector_type(2))) unsigned int u32x2;

__device__ __forceinline__ uint16_t f2bf(float f){
  uint32_t x = __float_as_uint(f);
  return (uint16_t)((x + 0x7FFFu + ((x>>16)&1u)) >> 16);   // RNE
}
__device__ __forceinline__ float bf2f(uint16_t u){ return __uint_as_float(((uint32_t)u)<<16); }
__device__ __forceinline__ uint32_t pack2(float a, float b){
  return (uint32_t)f2bf(a) | ((uint32_t)f2bf(b)<<16);
}
__device__ __forceinline__ void gld16(const uint16_t* g, uint16_t* l){
  __builtin_amdgcn_global_load_lds(
      (const __attribute__((address_space(1))) void*)g,
      (__attribute__((address_space(3))) void*)l, 16, 0, 0);
}

// ---- pre-pass: K -> KHI/KLO bf16, V -> V^T bf16, XOR-swizzled, chunk-major in ws ----
// K chunk layout (halves, per bh per chunk of 128 j): idx = j*64 + (k ^ ((j&7)<<3))
// V chunk layout (halves): idx = d*128 + (jl ^ ((d&7)<<3)), jl = j within chunk
// Grid (8, BHn): blockIdx.x -> chunk c = x>>1, half h = x&1 (64 rows per block).
extern "C" __global__ __launch_bounds__(256)
void attn_prep(const float* __restrict__ kg, const float* __restrict__ vg,
               uint16_t* __restrict__ khw, uint16_t* __restrict__ klw,
               uint16_t* __restrict__ vtw)
{
  const int t  = threadIdx.x;
  const int cx = blockIdx.x;
  const int c  = cx >> 1;             // j-chunk of 128
  const int h  = cx & 1;              // 64-row half of the chunk
  const int bh = blockIdx.y;
  const size_t base = (size_t)bh*(Ln*Dn);
  const size_t wsb  = ((size_t)bh<<15) + ((size_t)c<<13);   // chunk base (halves)

  // K: 64 rows; thread -> row sj = h*64 + (t>>2), half skh = (t>>1)&1, w2 pair (t&1)*2
  {
    const int sj  = h*64 + (t>>2);
    const int skh = (t>>1)&1;
    const int w2b = (t&1)*2;
    const float* kr = kg + base + (size_t)(c*128 + sj)*Dn + skh*32 + w2b*8;
    const int sx = (sj&7)<<3;
    #pragma unroll
    for (int w=0; w<2; ++w){
      const int w2 = w2b + w;
      f32x4 x0 = *(const f32x4*)(kr + w*8);
      f32x4 x1 = *(const f32x4*)(kr + w*8 + 4);
      uint32_t hw[4], lw[4];
      #pragma unroll
      for (int pi=0; pi<4; ++pi){
        float a0 = (pi<2) ? x0[pi*2]   : x1[(pi-2)*2];
        float a1 = (pi<2) ? x0[pi*2+1] : x1[(pi-2)*2+1];
        uint16_t h0 = f2bf(a0), h1 = f2bf(a1);
        hw[pi] = (uint32_t)h0 | ((uint32_t)h1<<16);
        lw[pi] = (uint32_t)f2bf(a0 - bf2f(h0)) | ((uint32_t)f2bf(a1 - bf2f(h1))<<16);
      }
      const size_t di = wsb + sj*64 + ((skh*32 + w2*8) ^ sx);
      *(u32x4*)(khw + di) = (u32x4){hw[0],hw[1],hw[2],hw[3]};
      *(u32x4*)(klw + di) = (u32x4){lw[0],lw[1],lw[2],lw[3]};
    }
  }

  // V: 64 rows: 4x4 register transpose -> VT[d][jl], swizzled
  {
    const int j0 = h*64 + (t>>4)*4;     // chunk-local j quad
    const int d0 = (t&15)*4;
    const float* vr = vg + base + (size_t)(c*128 + j0)*Dn + d0;
    f32x4 r0 = *(const f32x4*)(vr);
    f32x4 r1 = *(const f32x4*)(vr + Dn);
    f32x4 r2 = *(const f32x4*)(vr + 2*Dn);
    f32x4 r3 = *(const f32x4*)(vr + 3*Dn);
    #pragma unroll
    for (int qd=0; qd<4; ++qd){
      const int d = d0 + qd;
      u32x2 w; w.x = pack2(r0[qd], r1[qd]); w.y = pack2(r2[qd], r3[qd]);
      *(u32x2*)(vtw + wsb + d*128 + (j0 ^ ((d&7)<<3))) = w;
    }
  }
}

// ---- main: 64 q-rows/block, 4 waves x 16 rows; DMA-staged dbuf chunks ----
extern "C" __global__ __launch_bounds__(256, 2)
void attn_main2(const float* __restrict__ qg, const float* __restrict__ mg,
                const uint16_t* __restrict__ khw, const uint16_t* __restrict__ klw,
                const uint16_t* __restrict__ vtw, float* __restrict__ outg)
{
  // 64KB BIG: QK phase KH0[8192] KL0[8192] KH1[8192] KL1[8192] (halves)
  //           PV phase VT0[8192] VT1[8192] P[4 waves][2176]
  // + CMV[512] f32 column-mask terms (lgkm domain; keeps softmax off vmem)
  __shared__ __align__(16) uint16_t BIG[32768];
  __shared__ float CMV[512];

  const int t    = threadIdx.x;
  const int lane = t & 63;
  const int wv   = t >> 6;
  const int li   = lane & 15;
  const int lq   = lane >> 4;
  const int kx   = (li&7)<<3;          // swizzle XOR (halves)

  // XCD swizzle: lin%8 = XCD; XCD k owns bh [k*16,k*16+16)
  const int lin = blockIdx.x + (blockIdx.y << 3);
  const int xcd = lin & 7;
  const int jj  = lin >> 3;
  const int bh  = (xcd << 4) + (jj >> 3);
  const int b   = bh >> 3;
  const int i0  = (jj & 7)*64 + wv*16;

  const size_t base = (size_t)bh*(Ln*Dn);
  const float* mrow = mg + b*Ln;
  const size_t wsbh = (size_t)bh << 15;

  uint16_t* PW = BIG + 16384 + wv*2176;

  auto issueK = [&](int c, int bsel){
    const size_t so = wsbh + ((size_t)c<<13) + (wv<<11) + (lane<<3);
    uint16_t* dh = BIG + bsel*16384 + (wv<<11);
    #pragma unroll
    for (int i=0;i<4;++i){
      gld16(khw + so + i*512, dh + i*512);
      gld16(klw + so + i*512, dh + 8192 + i*512);
    }
  };
  auto issueV = [&](int c, int bsel){
    const size_t so = wsbh + ((size_t)c<<13) + (wv<<11) + (lane<<3);
    uint16_t* dv = BIG + bsel*8192 + (wv<<11);
    #pragma unroll
    for (int i=0;i<4;++i) gld16(vtw + so + i*512, dv + i*512);
  };

  // ---- prologue: Q + mask loads FIRST, then chunk-0 DMA (Q-waits leave DMA alive) ----
  const float* qrow = qg + base + (size_t)(i0 + li)*Dn;
  f32x4 qx0a = *(const f32x4*)(qrow + lq*8);
  f32x4 qx0b = *(const f32x4*)(qrow + lq*8 + 4);
  f32x4 qx1a = *(const f32x4*)(qrow + 32 + lq*8);
  f32x4 qx1b = *(const f32x4*)(qrow + 32 + lq*8 + 4);
  float m0 = mrow[t], m1 = mrow[t+256];
  float mv = mrow[i0 + li];

  issueK(0, 0);

  CMV[t]     = (m0 < -9000.f) ? 1e9f : m0;
  CMV[t+256] = (m1 < -9000.f) ? 1e9f : m1;
  const float rmv = (mv < -9000.f) ? 1e9f : mv;

  short8 qhi[2], qlo[2];
  #pragma unroll
  for (int kt=0; kt<2; ++kt){
    f32x4 xa = kt ? qx1a : qx0a;
    f32x4 xb = kt ? qx1b : qx0b;
    #pragma unroll
    for (int e=0; e<8; ++e){
      float x = (e<4) ? xa[e] : xb[e-4];
      uint16_t h = f2bf(x);
      qhi[kt][e] = (short)h;
      qlo[kt][e] = (short)f2bf(x - bf2f(h));
    }
  }

  f32x4 acc[32];
  #pragma unroll
  for (int j=0; j<32; ++j) acc[j] = (f32x4)0.f;

  // ---- QK: 4 chunks, double-buffered DMA; raw barriers + counted vmcnt ----
  #pragma unroll
  for (int c=0; c<4; ++c){
    if (c<3) issueK(c+1, (c+1)&1);
    if (c<3) asm volatile("s_waitcnt vmcnt(8)" ::: "memory");   // chunk c landed (mine)
    else     asm volatile("s_waitcnt vmcnt(4)" ::: "memory");   // K3 landed; V0 stays in flight
    __builtin_amdgcn_sched_barrier(0);
    __builtin_amdgcn_s_barrier();                                // all waves' portions landed
    __builtin_amdgcn_sched_barrier(0);
    const uint16_t* KHp = BIG + (c&1)*16384;
    const uint16_t* KLp = KHp + 8192;
    __builtin_amdgcn_s_setprio(1);
    #pragma unroll
    for (int jt=0; jt<8; ++jt){
      #pragma unroll
      for (int kt=0; kt<2; ++kt){
        const int idx = (jt*16 + li)*64 + ((kt*32 + lq*8) ^ kx);
        short8 kh = *(const short8*)(KHp + idx);
        short8 kl = *(const short8*)(KLp + idx);
        f32x4 A = acc[c*8+jt];
        A = __builtin_amdgcn_mfma_f32_16x16x32_bf16(kh, qhi[kt], A, 0,0,0);
        A = __builtin_amdgcn_mfma_f32_16x16x32_bf16(kl, qhi[kt], A, 0,0,0);
        A = __builtin_amdgcn_mfma_f32_16x16x32_bf16(kh, qlo[kt], A, 0,0,0);
        acc[c*8+jt] = A;
      }
    }
    __builtin_amdgcn_s_setprio(0);
    __builtin_amdgcn_sched_barrier(0);
    __builtin_amdgcn_s_barrier();                                // readers done before buf reuse
    __builtin_amdgcn_sched_barrier(0);
    if (c==2) issueV(0, 0);   // buf0 free after c=2 close; overlaps chunk-3 compute + softmax
  }

  // ---- mask + scale (CMV from LDS; pure lgkm/VALU — V0 DMA untouched) ----
  #pragma unroll
  for (int jt=0; jt<32; ++jt){
    f32x4 cm = *(const f32x4*)(CMV + jt*16 + lq*4);
    #pragma unroll
    for (int r=0; r<4; ++r)
      acc[jt][r] = (acc[jt][r]*0.125f - rmv) - cm[r];   // fp32 order matches ref
  }

  // ---- softmax over j (wave-local: lane owns full row across quads) ----
  float mx = -3.4e38f;
  #pragma unroll
  for (int jt=0; jt<32; ++jt)
    #pragma unroll
    for (int r=0; r<4; ++r) mx = fmaxf(mx, acc[jt][r]);
  mx = fmaxf(mx, __shfl_xor(mx, 16));
  mx = fmaxf(mx, __shfl_xor(mx, 32));
  float sum = 0.f;
  #pragma unroll
  for (int jt=0; jt<32; ++jt)
    #pragma unroll
    for (int r=0; r<4; ++r){ float e = __expf(acc[jt][r]-mx); acc[jt][r] = e; sum += e; }
  sum += __shfl_xor(sum, 16);
  sum += __shfl_xor(sum, 32);
  const float inv = 1.0f/sum;
  #pragma unroll
  for (int jt=0; jt<32; ++jt) acc[jt] = acc[jt]*inv;   // normalized P (also attn output)

  // ---- PV with per-chunk attn stores; ledger: 8 newest vmem = prev chunk's stores ----
  f32x4 oacc[4];
  #pragma unroll
  for (int dt=0; dt<4; ++dt) oacc[dt] = (f32x4)0.f;

  float* arow = outg + AOFF + (size_t)bh*Ln*Ln + (size_t)(i0+li)*Ln;

  #pragma unroll
  for (int c=0; c<4; ++c){
    // P pack hoisted: pure VALU on acc, done before the wait so the post-barrier
    // path is ds_write -> lgkmcnt -> MFMA with no VALU preamble.
    u32x2 pwreg[8];
    #pragma unroll
    for (int jtl=0; jtl<8; ++jtl){
      const f32x4 p = acc[c*8+jtl];
      pwreg[jtl].x = pack2(p[0], p[1]);
      pwreg[jtl].y = pack2(p[2], p[3]);
    }
    if (c==0) asm volatile("s_waitcnt vmcnt(0)" ::: "memory");   // V0 landed (only V0 out)
    else      asm volatile("s_waitcnt vmcnt(8)" ::: "memory");   // V_c landed; prev stores fly
    __builtin_amdgcn_sched_barrier(0);
    __builtin_amdgcn_s_barrier();                                 // all waves; gates buf reuse
    __builtin_amdgcn_sched_barrier(0);
    if (c<3) issueV(c+1, (c+1)&1);
    #pragma unroll
    for (int jtl=0; jtl<8; ++jtl)                                 // P chunk rows (wave-private)
      *(u32x2*)(PW + li*136 + jtl*16 + lq*4) = pwreg[jtl];
    asm volatile("s_waitcnt lgkmcnt(0)" ::: "memory");            // P visible within wave
    __builtin_amdgcn_sched_barrier(0);
    const uint16_t* VTp = BIG + (c&1)*8192;
    __builtin_amdgcn_s_setprio(1);
    #pragma unroll
    for (int c32=0; c32<4; ++c32){
      short8 pf = *(const short8*)(PW + li*136 + c32*32 + lq*8);           // P^T B-frag
      #pragma unroll
      for (int dt=0; dt<4; ++dt){
        short8 vb = *(const short8*)(VTp + (dt*16+li)*128 + ((c32*32+lq*8) ^ kx)); // V^T A-frag
        oacc[dt] = __builtin_amdgcn_mfma_f32_16x16x32_bf16(vb, pf, oacc[dt], 0,0,0);
      }
    }
    __builtin_amdgcn_s_setprio(0);
    // attn stores for chunk c (8 f32x4/lane) — NORMAL stores: L2 merges the
    // 64B pieces written by this wave this phase into full 128B lines.
    #pragma unroll
    for (int jtl=0; jtl<8; ++jtl)
      *(f32x4*)(arow + (c*8+jtl)*16 + lq*4) = acc[c*8+jtl];
  }

  // ---- store O (O^T C-layout) ----
  #pragma unroll
  for (int dt=0; dt<4; ++dt)
    *(f32x4*)(outg + base + (size_t)(i0+li)*Dn + dt*16 + lq*4) = oacc[dt];
}

// ---------------- fallback (round-5 kernel) if workspace is too small ----------------
#define KSTR  72
#define VTSTR 136
#define FPSTRH 136

extern "C" __global__ __launch_bounds__(256, 2)
void attn_mfma(const float* __restrict__ qg, const float* __restrict__ kg,
               const float* __restrict__ vg, const float* __restrict__ mg,
               float* __restrict__ outg)
{
  __shared__ uint4 ldsraw[(36864 + 2048)/16];
  uint16_t* KHI = (uint16_t*)ldsraw;
  uint16_t* KLO = KHI + 128*KSTR;
  uint16_t* VT  = (uint16_t*)ldsraw;
  float*    CMV = (float*)((char*)ldsraw + 36864);

  const int t    = threadIdx.x;
  const int lane = t & 63;
  const int wv   = t >> 6;
  const int li   = lane & 15;
  const int lq   = lane >> 4;

  const int lin = blockIdx.x + (blockIdx.y << 3);
  const int xcd = lin & 7;
  const int jj  = lin >> 3;
  const int bh  = (xcd << 4) + (jj >> 3);
  const int b   = bh >> 3;
  const int i0  = (jj & 7)*64 + wv*16;

  const size_t base = (size_t)bh*(Ln*Dn);
  const float* mrow = mg + b*Ln;

  uint16_t* PW = (uint16_t*)((char*)ldsraw + 17408 + wv*(16*FPSTRH*2));

  {
    float m0 = mrow[t], m1 = mrow[t+256];
    CMV[t]     = (m0 < -9000.f) ? 1e9f : m0;
    CMV[t+256] = (m1 < -9000.f) ? 1e9f : m1;
  }

  short8 qhi[2], qlo[2];
  {
    const float* qrow = qg + base + (size_t)(i0 + li)*Dn;
    #pragma unroll
    for (int kt=0; kt<2; ++kt){
      const float* p = qrow + kt*32 + lq*8;
      f32x4 x0 = *(const f32x4*)p;
      f32x4 x1 = *(const f32x4*)(p+4);
      #pragma unroll
      for (int e=0; e<8; ++e){
        float x = (e<4) ? x0[e] : x1[e-4];
        uint16_t h = f2bf(x);
        qhi[kt][e] = (short)h;
        qlo[kt][e] = (short)f2bf(x - bf2f(h));
      }
    }
  }

  f32x4 acc[32];
  #pragma unroll
  for (int j=0; j<32; ++j) acc[j] = (f32x4)0.f;

  const int sj = t>>1, skh = t&1;
  #pragma unroll
  for (int c=0; c<4; ++c){
    __syncthreads();
    {
      const float* kr = kg + base + (size_t)(c*128 + sj)*Dn + skh*32;
      uint16_t* dhi = KHI + sj*KSTR + skh*32;
      uint16_t* dlo = KLO + sj*KSTR + skh*32;
      #pragma unroll
      for (int w2=0; w2<4; ++w2){
        f32x4 x0 = *(const f32x4*)(kr + w2*8);
        f32x4 x1 = *(const f32x4*)(kr + w2*8 + 4);
        uint32_t hw[4], lw[4];
        #pragma unroll
        for (int pi=0; pi<4; ++pi){
          float a0 = (pi<2) ? x0[pi*2]   : x1[(pi-2)*2];
          float a1 = (pi<2) ? x0[pi*2+1] : x1[(pi-2)*2+1];
          uint16_t h0 = f2bf(a0), h1 = f2bf(a1);
          hw[pi] = (uint32_t)h0 | ((uint32_t)h1<<16);
          lw[pi] = (uint32_t)f2bf(a0 - bf2f(h0)) | ((uint32_t)f2bf(a1 - bf2f(h1))<<16);
        }
        *(u32x4*)(dhi + w2*8) = (u32x4){hw[0],hw[1],hw[2],hw[3]};
        *(u32x4*)(dlo + w2*8) = (u32x4){lw[0],lw[1],lw[2],lw[3]};
      }
    }
    __syncthreads();
    #pragma unroll
    for (int jt=0; jt<8; ++jt){
      #pragma unroll
      for (int kt=0; kt<2; ++kt){
        const int off = (jt*16 + li)*KSTR + kt*32 + lq*8;
        short8 kh = *(const short8*)(KHI + off);
        short8 kl = *(const short8*)(KLO + off);
        f32x4 A = acc[c*8+jt];
        A = __builtin_amdgcn_mfma_f32_16x16x32_bf16(kh, qhi[kt], A, 0,0,0);
        A = __builtin_amdgcn_mfma_f32_16x16x32_bf16(kl, qhi[kt], A, 0,0,0);
        A = __builtin_amdgcn_mfma_f32_16x16x32_bf16(kh, qlo[kt], A, 0,0,0);
        acc[c*8+jt] = A;
      }
    }
  }

  {
    float mv = mrow[i0 + li];
    const float rmv = (mv < -9000.f) ? 1e9f : mv;
    #pragma unroll
    for (int jt=0; jt<32; ++jt){
      f32x4 cm = *(const f32x4*)(CMV + jt*16 + lq*4);
      #pragma unroll
      for (int r=0; r<4; ++r)
        acc[jt][r] = (acc[jt][r]*0.125f - rmv) - cm[r];
    }
  }
  float mx = -3.4e38f;
  #pragma unroll
  for (int jt=0; jt<32; ++jt)
    #pragma unroll
    for (int r=0; r<4; ++r) mx = fmaxf(mx, acc[jt][r]);
  mx = fmaxf(mx, __shfl_xor(mx, 16));
  mx = fmaxf(mx, __shfl_xor(mx, 32));
  float sum = 0.f;
  #pragma unroll
  for (int jt=0; jt<32; ++jt)
    #pragma unroll
    for (int r=0; r<4; ++r){ float e = __expf(acc[jt][r]-mx); acc[jt][r] = e; sum += e; }
  sum += __shfl_xor(sum, 16);
  sum += __shfl_xor(sum, 32);
  const float inv = 1.0f/sum;

  {
    float* arow = outg + AOFF + (size_t)bh*Ln*Ln + (size_t)(i0+li)*Ln;
    #pragma unroll
    for (int jt=0; jt<32; ++jt){
      f32x4 p = acc[jt]*inv;
      acc[jt] = p;
      *(f32x4*)(arow + jt*16 + lq*4) = p;
    }
  }

  f32x4 oacc[4];
  #pragma unroll
  for (int dt=0; dt<4; ++dt) oacc[dt] = (f32x4)0.f;

  #pragma unroll
  for (int c=0; c<4; ++c){
    __syncthreads();
    #pragma unroll
    for (int it=0; it<2; ++it){
      const int j0 = (t>>4)*4 + it*64;
      const int d0 = (t&15)*4;
      const float* vr = vg + base + (size_t)(c*128 + j0)*Dn + d0;
      f32x4 r0 = *(const f32x4*)(vr);
      f32x4 r1 = *(const f32x4*)(vr + Dn);
      f32x4 r2 = *(const f32x4*)(vr + 2*Dn);
      f32x4 r3 = *(const f32x4*)(vr + 3*Dn);
      #pragma unroll
      for (int qd=0; qd<4; ++qd){
        u32x2 w; w.x = pack2(r0[qd], r1[qd]); w.y = pack2(r2[qd], r3[qd]);
        *(u32x2*)(VT + (d0+qd)*VTSTR + j0) = w;
      }
    }
    __syncthreads();
    #pragma unroll
    for (int jtl=0; jtl<8; ++jtl){
      const f32x4 p = acc[c*8+jtl];
      u32x2 w; w.x = pack2(p[0], p[1]); w.y = pack2(p[2], p[3]);
      *(u32x2*)(PW + li*FPSTRH + jtl*16 + lq*4) = w;
    }
    asm volatile("s_waitcnt lgkmcnt(0)" ::: "memory");
    #pragma unroll
    for (int c32=0; c32<4; ++c32){
      short8 pf = *(const short8*)(PW + li*FPSTRH + c32*32 + lq*8);
      #pragma unroll
      for (int dt=0; dt<4; ++dt){
        short8 vb = *(const short8*)(VT + (dt*16+li)*VTSTR + c32*32 + lq*8);
        oacc[dt] = __builtin_amdgcn_mfma_f32_16x16x32_bf16(vb, pf, oacc[dt], 0,0,0);
      }
    }
  }

  #pragma unroll
  for (int dt=0; dt<4; ++dt)
    *(f32x4*)(outg + base + (size_t)(i0+li)*Dn + dt*16 + lq*4) = oacc[dt];
}

extern "C" void kernel_launch(void* const* d_in, const int* in_sizes, int n_in,
                              void* d_out, int out_size, void* d_ws, size_t ws_size,
                              hipStream_t stream)
{
  (void)in_sizes; (void)n_in; (void)out_size;
  const float* qg = (const float*)d_in[0];
  const float* kg = (const float*)d_in[1];
  const float* vg = (const float*)d_in[2];
  const float* mg = (const float*)d_in[3];
  float* outg = (float*)d_out;

  const size_t WS_NEED = 25165824;   // KHI 8.39MB + KLO 8.39MB + VT 8.39MB
  if (d_ws && ws_size >= WS_NEED){
    uint16_t* khw = (uint16_t*)d_ws;
    uint16_t* klw = (uint16_t*)((char*)d_ws + 8388608);
    uint16_t* vtw = (uint16_t*)((char*)d_ws + 16777216);
    attn_prep<<<dim3(8, BHn), 256, 0, stream>>>(kg, vg, khw, klw, vtw);
    attn_main2<<<dim3(Ln/64, BHn), 256, 0, stream>>>(qg, mg, khw, klw, vtw, outg);
  } else {
    attn_mfma<<<dim3(Ln/64, BHn), 256, 0, stream>>>(qg, kg, vg, mg, outg);
  }
}